// Round 3
// baseline (256.090 us; speedup 1.0000x reference)
//
#include <hip/hip_runtime.h>
#include <hip/hip_bf16.h>

#define S_DIM 128
#define R_DIM 256
#define CM    256
#define CH    32
#define CZ    128

using bf16x8 = __attribute__((ext_vector_type(8))) short;
using f32x4  = __attribute__((ext_vector_type(4))) float;

static __device__ __forceinline__ unsigned short f2bf(float f) {
    __hip_bfloat16 h = __float2bfloat16(f);
    return *reinterpret_cast<unsigned short*>(&h);
}

// ---------------------------------------------------------------------------
// Prep (merged): w12T [h64][c256] bf16 | wT [z128][k1024] bf16 | recip norm
// ---------------------------------------------------------------------------
__global__ __launch_bounds__(256)
void prep_kernel(const float* __restrict__ w1, const float* __restrict__ w2,
                 const float* __restrict__ w_out, const float* __restrict__ mask,
                 __hip_bfloat16* __restrict__ w12T, __hip_bfloat16* __restrict__ wT,
                 float* __restrict__ rcp)
{
    const int b = blockIdx.x, tid = threadIdx.x;
    if (b < 64) {
        const int idx = b * 256 + tid;                 // 16384
        const int h = idx >> 8, c = idx & 255;
        const float v = (h < 32) ? w1[c * CH + h] : w2[c * CH + (h - 32)];
        w12T[idx] = __float2bfloat16(v);
    } else if (b < 576) {
        const int idx = (b - 64) * 256 + tid;          // 131072
        const int k = idx >> 7, z = idx & 127;
        wT[z * 1024 + k] = __float2bfloat16(w_out[idx]);
    } else {
        const int i = b - 576, j = tid;                // 256 x 256
        float acc = 0.f;
        for (int s = 0; s < S_DIM; ++s)
            acc += mask[s * R_DIM + i] * mask[s * R_DIM + j];
        rcp[i * R_DIM + j] = 1.0f / (acc + 1e-3f);
    }
}

// ---------------------------------------------------------------------------
// Kernel 1: LayerNorm -> bf16 LDS tile -> MFMA 256->64 projection
// wg covers 2 r x 16 s (32 rows). m-tile rows = s-local -> epilogue packs
// 4 consecutive s into one ushort4 store (coalesced 32B chunks).
// a_t/b_t layout: [r][h][s]
// ---------------------------------------------------------------------------
__global__ __launch_bounds__(256)
void ln_proj_kernel(const float* __restrict__ m, const float* __restrict__ mask,
                    const float* __restrict__ ls, const float* __restrict__ lb,
                    const __hip_bfloat16* __restrict__ w12T,
                    const float* __restrict__ b1v, const float* __restrict__ b2v,
                    __hip_bfloat16* __restrict__ a_t, __hip_bfloat16* __restrict__ b_t)
{
    __shared__ unsigned short X[32 * 256];   // 16 KB
    const int tid  = threadIdx.x;
    const int wave = tid >> 6, lane = tid & 63;
    const int l16 = lane & 15, l4 = lane >> 4;
    const int rb = blockIdx.x & 127, sb = blockIdx.x >> 7;
    const int r0 = rb * 2, s0 = sb * 16;
    char* Xb = reinterpret_cast<char*>(X);

    const float4 sc = *reinterpret_cast<const float4*>(ls + lane * 4);
    const float4 bi = *reinterpret_cast<const float4*>(lb + lane * 4);

    for (int rep = 0; rep < 8; ++rep) {
        const int row = wave * 8 + rep;          // row = rl*16 + sl
        const int rl = row >> 4, sl = row & 15;
        const float4 x = *reinterpret_cast<const float4*>(
            m + ((size_t)(s0 + sl) * R_DIM + r0 + rl) * CM + lane * 4);
        float sum = x.x + x.y + x.z + x.w;
        float sq  = x.x * x.x + x.y * x.y + x.z * x.z + x.w * x.w;
        #pragma unroll
        for (int off = 32; off; off >>= 1) {
            sum += __shfl_xor(sum, off);
            sq  += __shfl_xor(sq, off);
        }
        const float mu = sum * (1.0f / CM);
        const float rs = rsqrtf(sq * (1.0f / CM) - mu * mu + 1e-5f);
        ushort4 o;
        o.x = f2bf((x.x - mu) * rs * sc.x + bi.x);
        o.y = f2bf((x.y - mu) * rs * sc.y + bi.y);
        o.z = f2bf((x.z - mu) * rs * sc.z + bi.z);
        o.w = f2bf((x.w - mu) * rs * sc.w + bi.w);
        const int byte = (row * 512 + lane * 8) ^ ((row & 7) << 4);
        *reinterpret_cast<ushort4*>(Xb + byte) = o;
    }
    __syncthreads();

    // waves: wm = m-tile (16 rows = 1 r x 16 s), wn = a|b half
    const int wm = wave >> 1, wn = wave & 1;
    const f32x4 zero = {0.f, 0.f, 0.f, 0.f};
    f32x4 acc[2];
    acc[0] = zero; acc[1] = zero;
    const int arow = wm * 16 + l16;
    const int asw  = (arow & 7) << 4;
    const char* arb = Xb + arow * 512;
    const __hip_bfloat16* wbase = w12T + (size_t)(wn * 32 + l16) * CM + l4 * 8;

    #pragma unroll
    for (int kb = 0; kb < 8; ++kb) {
        const bf16x8 af = *reinterpret_cast<const bf16x8*>(arb + ((kb * 64 + l4 * 16) ^ asw));
        #pragma unroll
        for (int nt = 0; nt < 2; ++nt) {
            const bf16x8 bf = *reinterpret_cast<const bf16x8*>(wbase + nt * 16 * CM + kb * 32);
            acc[nt] = __builtin_amdgcn_mfma_f32_16x16x32_bf16(af, bf, acc[nt], 0, 0, 0);
        }
    }

    __hip_bfloat16* dst = wn ? b_t : a_t;
    const float*    bv  = wn ? b2v : b1v;
    const int r = r0 + wm;
    float mk[4];
    #pragma unroll
    for (int t = 0; t < 4; ++t)
        mk[t] = mask[(s0 + l4 * 4 + t) * R_DIM + r];   // D-row = s-local = l4*4+t

    #pragma unroll
    for (int nt = 0; nt < 2; ++nt) {
        const int h = nt * 16 + l16;
        const float bo = bv[h];
        ushort4 o;
        o.x = f2bf((acc[nt][0] + bo) * mk[0]);
        o.y = f2bf((acc[nt][1] + bo) * mk[1]);
        o.z = f2bf((acc[nt][2] + bo) * mk[2]);
        o.w = f2bf((acc[nt][3] + bo) * mk[3]);
        *reinterpret_cast<ushort4*>(
            reinterpret_cast<unsigned short*>(dst) +
            (size_t)r * (CH * S_DIM) + h * S_DIM + s0 + l4 * 4) = o;
    }
}

// ---------------------------------------------------------------------------
// Kernel 2: fused outer-product (K=S=128) + w_out projection (K=1024)
// WG = 8 i x 8 j, processed as two 32-pair halves -> 64 KB LDS -> 2 wgs/CU.
// Phase-1 writes carry an extra c-based XOR so the four l4 groups hit
// disjoint bank regions (kills the 7-way write conflict).
// ---------------------------------------------------------------------------
__global__ __launch_bounds__(512, 4)
void fused_kernel(const __hip_bfloat16* __restrict__ a_t,
                  const __hip_bfloat16* __restrict__ b_t,
                  const __hip_bfloat16* __restrict__ wT,
                  const float* __restrict__ b_out,
                  const float* __restrict__ recip,
                  float* __restrict__ out)
{
    __shared__ __hip_bfloat16 outer_lds[32 * 1024];   // 64 KB
    const int tid  = threadIdx.x;
    const int wave = tid >> 6, lane = tid & 63;
    const int l16 = lane & 15, l4 = lane >> 4;
    const int i0 = blockIdx.y * 8, j0 = blockIdx.x * 8;
    char* ldsb = reinterpret_cast<char*>(outer_lds);

    // a-fragments for this wave's i, held across both halves
    const int i = i0 + wave;
    const __hip_bfloat16* abase = a_t + (size_t)i * (CH * S_DIM) + l16 * S_DIM + l4 * 8;
    bf16x8 afr[2][4];
    #pragma unroll
    for (int ch = 0; ch < 2; ++ch)
        #pragma unroll
        for (int kk = 0; kk < 4; ++kk)
            afr[ch][kk] = *reinterpret_cast<const bf16x8*>(abase + ch * 16 * S_DIM + kk * 32);

    for (int half = 0; half < 2; ++half) {
        // ---- phase 1: 4 outer products per wave -> LDS [32][1024] ----
        for (int jj = 0; jj < 4; ++jj) {
            const int j = j0 + half * 4 + jj;
            const __hip_bfloat16* bbase = b_t + (size_t)j * (CH * S_DIM) + l16 * S_DIM + l4 * 8;
            bf16x8 bfr[2][4];
            #pragma unroll
            for (int eh = 0; eh < 2; ++eh)
                #pragma unroll
                for (int kk = 0; kk < 4; ++kk)
                    bfr[eh][kk] = *reinterpret_cast<const bf16x8*>(bbase + eh * 16 * S_DIM + kk * 32);

            const f32x4 zero = {0.f, 0.f, 0.f, 0.f};
            f32x4 acc[2][2];
            acc[0][0] = zero; acc[0][1] = zero; acc[1][0] = zero; acc[1][1] = zero;
            #pragma unroll
            for (int kk = 0; kk < 4; ++kk) {
                acc[0][0] = __builtin_amdgcn_mfma_f32_16x16x32_bf16(afr[0][kk], bfr[0][kk], acc[0][0], 0, 0, 0);
                acc[0][1] = __builtin_amdgcn_mfma_f32_16x16x32_bf16(afr[0][kk], bfr[1][kk], acc[0][1], 0, 0, 0);
                acc[1][0] = __builtin_amdgcn_mfma_f32_16x16x32_bf16(afr[1][kk], bfr[0][kk], acc[1][0], 0, 0, 0);
                acc[1][1] = __builtin_amdgcn_mfma_f32_16x16x32_bf16(afr[1][kk], bfr[1][kk], acc[1][1], 0, 0, 0);
            }
            const int pair = wave * 4 + jj;            // 0..31 within half
            char* rowb = ldsb + pair * 2048;
            const int sw = (pair & 7) << 4;
            #pragma unroll
            for (int ch = 0; ch < 2; ++ch)
                #pragma unroll
                for (int eh = 0; eh < 2; ++eh)
                    #pragma unroll
                    for (int t = 0; t < 4; ++t) {
                        const int c = ch * 16 + l4 * 4 + t;   // D row = l4*4+t
                        const int e = eh * 16 + l16;          // D col = l16
                        const int byte = ((c * 32 + e) * 2) ^ sw ^ (((c >> 2) & 3) << 5);
                        *reinterpret_cast<__hip_bfloat16*>(rowb + byte) = __float2bfloat16(acc[ch][eh][t]);
                    }
        }
        __syncthreads();

        // ---- phase 2: [32 pairs x 1024] @ wT^T -> [32 x 128] ----
        {
            const __hip_bfloat16* wbase = wT + (size_t)(wave * 16 + l16) * 1024 + l4 * 8;
            const f32x4 zero = {0.f, 0.f, 0.f, 0.f};
            f32x4 pacc[2];
            pacc[0] = zero; pacc[1] = zero;
            bf16x8 bfn = *reinterpret_cast<const bf16x8*>(wbase);
            for (int kb = 0; kb < 32; ++kb) {
                const bf16x8 bfc = bfn;
                bfn = *reinterpret_cast<const bf16x8*>(wbase + (((kb + 1) & 31)) * 32);
                #pragma unroll
                for (int mt = 0; mt < 2; ++mt) {
                    const int row = mt * 16 + l16;
                    const bf16x8 af = *reinterpret_cast<const bf16x8*>(
                        ldsb + row * 2048 +
                        ((kb * 64 + l4 * 16) ^ ((row & 7) << 4) ^ (((kb >> 2) & 3) << 5)));
                    pacc[mt] = __builtin_amdgcn_mfma_f32_16x16x32_bf16(af, bfc, pacc[mt], 0, 0, 0);
                }
            }
            const int z = wave * 16 + l16;
            const float bo = b_out[z];
            #pragma unroll
            for (int mt = 0; mt < 2; ++mt) {
                #pragma unroll
                for (int t = 0; t < 4; ++t) {
                    const int pl = mt * 16 + l4 * 4 + t;          // pair-local
                    const int oi = i0 + (pl >> 2), oj = j0 + half * 4 + (pl & 3);
                    out[((size_t)oi * R_DIM + oj) * CZ + z] =
                        (pacc[mt][t] + bo) * recip[oi * R_DIM + oj];
                }
            }
        }
        __syncthreads();   // protect next half's phase-1 writes
    }
}

// ---------------------------------------------------------------------------
extern "C" void kernel_launch(void* const* d_in, const int* in_sizes, int n_in,
                              void* d_out, int out_size, void* d_ws, size_t ws_size,
                              hipStream_t stream)
{
    const float* m     = (const float*)d_in[0];
    const float* mask  = (const float*)d_in[1];
    const float* ln_s  = (const float*)d_in[2];
    const float* ln_b  = (const float*)d_in[3];
    const float* w1    = (const float*)d_in[4];
    const float* b1    = (const float*)d_in[5];
    const float* w2    = (const float*)d_in[6];
    const float* b2    = (const float*)d_in[7];
    const float* w_out = (const float*)d_in[8];
    const float* b_out = (const float*)d_in[9];
    float* out = (float*)d_out;

    char* ws = (char*)d_ws;
    __hip_bfloat16* a_t  = (__hip_bfloat16*)(ws);                                    // 2 MB
    __hip_bfloat16* b_t  = (__hip_bfloat16*)(ws + (size_t)(2u << 20));               // 2 MB
    __hip_bfloat16* wT   = (__hip_bfloat16*)(ws + (size_t)(4u << 20));               // 256 KB
    float*          rcp  = (float*)(ws + (size_t)(4u << 20) + (size_t)(256u << 10)); // 256 KB
    __hip_bfloat16* w12T = (__hip_bfloat16*)(ws + (size_t)(4u << 20) + (size_t)(512u << 10)); // 32 KB

    prep_kernel<<<832, 256, 0, stream>>>(w1, w2, w_out, mask, w12T, wT, rcp);
    ln_proj_kernel<<<1024, 256, 0, stream>>>(m, mask, ln_s, ln_b, w12T, b1, b2, a_t, b_t);
    fused_kernel<<<dim3(32, 32), 512, 0, stream>>>(a_t, b_t, wT, b_out, rcp, out);
}

// Round 4
// 236.039 us; speedup vs baseline: 1.0849x; 1.0849x over previous
//
#include <hip/hip_runtime.h>
#include <hip/hip_bf16.h>

#define S_DIM 128
#define R_DIM 256
#define CM    256
#define CH    32
#define CZ    128

using bf16x8 = __attribute__((ext_vector_type(8))) short;
using f32x4  = __attribute__((ext_vector_type(4))) float;

static __device__ __forceinline__ unsigned short f2bf(float f) {
    __hip_bfloat16 h = __float2bfloat16(f);
    return *reinterpret_cast<unsigned short*>(&h);
}

// ---------------------------------------------------------------------------
// Prep (merged): w12T [h64][c256] bf16 | wTp [z128][k'=e*32+c] bf16 | recip
// k' permutation: phase-2 A-frags read the outer tile as [e][c]; B must use
// the same k-order, so wTp[z][e*32+c] = w_out[(c*32+e)][z].
// ---------------------------------------------------------------------------
__global__ __launch_bounds__(256)
void prep_kernel(const float* __restrict__ w1, const float* __restrict__ w2,
                 const float* __restrict__ w_out, const float* __restrict__ mask,
                 __hip_bfloat16* __restrict__ w12T, __hip_bfloat16* __restrict__ wT,
                 float* __restrict__ rcp)
{
    const int b = blockIdx.x, tid = threadIdx.x;
    if (b < 64) {
        const int idx = b * 256 + tid;                 // 16384
        const int h = idx >> 8, c = idx & 255;
        const float v = (h < 32) ? w1[c * CH + h] : w2[c * CH + (h - 32)];
        w12T[idx] = __float2bfloat16(v);
    } else if (b < 576) {
        const int idx = (b - 64) * 256 + tid;          // 131072, dest-ordered
        const int z = idx >> 10, kp = idx & 1023;
        const int e = kp >> 5, c = kp & 31;
        wT[idx] = __float2bfloat16(w_out[(c * 32 + e) * CZ + z]);
    } else {
        const int i = b - 576, j = tid;                // 256 x 256
        float acc = 0.f;
        for (int s = 0; s < S_DIM; ++s)
            acc += mask[s * R_DIM + i] * mask[s * R_DIM + j];
        rcp[i * R_DIM + j] = 1.0f / (acc + 1e-3f);
    }
}

// ---------------------------------------------------------------------------
// Kernel 1: LayerNorm -> bf16 LDS tile -> MFMA 256->64 projection
// wg covers 2 r x 16 s (32 rows); epilogue packs 4 consecutive s per store.
// a_t/b_t layout: [r][h][s]
// ---------------------------------------------------------------------------
__global__ __launch_bounds__(256)
void ln_proj_kernel(const float* __restrict__ m, const float* __restrict__ mask,
                    const float* __restrict__ ls, const float* __restrict__ lb,
                    const __hip_bfloat16* __restrict__ w12T,
                    const float* __restrict__ b1v, const float* __restrict__ b2v,
                    __hip_bfloat16* __restrict__ a_t, __hip_bfloat16* __restrict__ b_t)
{
    __shared__ unsigned short X[32 * 256];   // 16 KB
    const int tid  = threadIdx.x;
    const int wave = tid >> 6, lane = tid & 63;
    const int l16 = lane & 15, l4 = lane >> 4;
    const int rb = blockIdx.x & 127, sb = blockIdx.x >> 7;
    const int r0 = rb * 2, s0 = sb * 16;
    char* Xb = reinterpret_cast<char*>(X);

    const float4 sc = *reinterpret_cast<const float4*>(ls + lane * 4);
    const float4 bi = *reinterpret_cast<const float4*>(lb + lane * 4);

    for (int rep = 0; rep < 8; ++rep) {
        const int row = wave * 8 + rep;          // row = rl*16 + sl
        const int rl = row >> 4, sl = row & 15;
        const float4 x = *reinterpret_cast<const float4*>(
            m + ((size_t)(s0 + sl) * R_DIM + r0 + rl) * CM + lane * 4);
        float sum = x.x + x.y + x.z + x.w;
        float sq  = x.x * x.x + x.y * x.y + x.z * x.z + x.w * x.w;
        #pragma unroll
        for (int off = 32; off; off >>= 1) {
            sum += __shfl_xor(sum, off);
            sq  += __shfl_xor(sq, off);
        }
        const float mu = sum * (1.0f / CM);
        const float rs = rsqrtf(sq * (1.0f / CM) - mu * mu + 1e-5f);
        ushort4 o;
        o.x = f2bf((x.x - mu) * rs * sc.x + bi.x);
        o.y = f2bf((x.y - mu) * rs * sc.y + bi.y);
        o.z = f2bf((x.z - mu) * rs * sc.z + bi.z);
        o.w = f2bf((x.w - mu) * rs * sc.w + bi.w);
        const int byte = (row * 512 + lane * 8) ^ ((row & 7) << 4);
        *reinterpret_cast<ushort4*>(Xb + byte) = o;
    }
    __syncthreads();

    // waves: wm = m-tile (16 rows = 1 r x 16 s), wn = a|b half
    const int wm = wave >> 1, wn = wave & 1;
    const f32x4 zero = {0.f, 0.f, 0.f, 0.f};
    f32x4 acc[2];
    acc[0] = zero; acc[1] = zero;
    const int arow = wm * 16 + l16;
    const int asw  = (arow & 7) << 4;
    const char* arb = Xb + arow * 512;
    const __hip_bfloat16* wbase = w12T + (size_t)(wn * 32 + l16) * CM + l4 * 8;

    #pragma unroll
    for (int kb = 0; kb < 8; ++kb) {
        const bf16x8 af = *reinterpret_cast<const bf16x8*>(arb + ((kb * 64 + l4 * 16) ^ asw));
        #pragma unroll
        for (int nt = 0; nt < 2; ++nt) {
            const bf16x8 bf = *reinterpret_cast<const bf16x8*>(wbase + nt * 16 * CM + kb * 32);
            acc[nt] = __builtin_amdgcn_mfma_f32_16x16x32_bf16(af, bf, acc[nt], 0, 0, 0);
        }
    }

    __hip_bfloat16* dst = wn ? b_t : a_t;
    const float*    bv  = wn ? b2v : b1v;
    const int r = r0 + wm;
    float mk[4];
    #pragma unroll
    for (int t = 0; t < 4; ++t)
        mk[t] = mask[(s0 + l4 * 4 + t) * R_DIM + r];   // D-row = s-local = l4*4+t

    #pragma unroll
    for (int nt = 0; nt < 2; ++nt) {
        const int h = nt * 16 + l16;
        const float bo = bv[h];
        ushort4 o;
        o.x = f2bf((acc[nt][0] + bo) * mk[0]);
        o.y = f2bf((acc[nt][1] + bo) * mk[1]);
        o.z = f2bf((acc[nt][2] + bo) * mk[2]);
        o.w = f2bf((acc[nt][3] + bo) * mk[3]);
        *reinterpret_cast<ushort4*>(
            reinterpret_cast<unsigned short*>(dst) +
            (size_t)r * (CH * S_DIM) + h * S_DIM + s0 + l4 * 4) = o;
    }
}

// ---------------------------------------------------------------------------
// Kernel 2: fused outer-product (K=S=128) + w_out projection (K'=1024)
// WG = 8 i x 8 j, two 32-pair halves -> 64 KB LDS -> 2 wgs/CU.
// Outer tile stored TRANSPOSED [pair][e][c]: D-frag's 4 regs are 4
// consecutive c -> one ds_write_b64 per (ch,eh) (4 writes/j, ~2-way).
// Phase-2 A reads 8 consecutive c at e=kb (contiguous b128); B uses the
// matching k'=e*32+c order via wTp.
// Swizzle: byte ^= ((e&3)<<4) ^ ((pair&7)<<4)  (16B-granular, b64/b128-safe).
// ---------------------------------------------------------------------------
__global__ __launch_bounds__(512)
void fused_kernel(const __hip_bfloat16* __restrict__ a_t,
                  const __hip_bfloat16* __restrict__ b_t,
                  const __hip_bfloat16* __restrict__ wT,
                  const float* __restrict__ b_out,
                  const float* __restrict__ recip,
                  float* __restrict__ out)
{
    __shared__ __hip_bfloat16 outer_lds[32 * 1024];   // 64 KB
    const int tid  = threadIdx.x;
    const int wave = tid >> 6, lane = tid & 63;
    const int l16 = lane & 15, l4 = lane >> 4;
    const int i0 = blockIdx.y * 8, j0 = blockIdx.x * 8;
    char* ldsb = reinterpret_cast<char*>(outer_lds);

    // a-fragments for this wave's i, held across both halves
    const int i = i0 + wave;
    const __hip_bfloat16* abase = a_t + (size_t)i * (CH * S_DIM) + l16 * S_DIM + l4 * 8;
    bf16x8 afr[2][4];
    #pragma unroll
    for (int ch = 0; ch < 2; ++ch)
        #pragma unroll
        for (int kk = 0; kk < 4; ++kk)
            afr[ch][kk] = *reinterpret_cast<const bf16x8*>(abase + ch * 16 * S_DIM + kk * 32);

    for (int half = 0; half < 2; ++half) {
        // ---- phase 1: 4 outer products per wave -> LDS [32][e32][c32] ----
        for (int jj = 0; jj < 4; ++jj) {
            const int j = j0 + half * 4 + jj;
            const __hip_bfloat16* bbase = b_t + (size_t)j * (CH * S_DIM) + l16 * S_DIM + l4 * 8;
            bf16x8 bfr[2][4];
            #pragma unroll
            for (int eh = 0; eh < 2; ++eh)
                #pragma unroll
                for (int kk = 0; kk < 4; ++kk)
                    bfr[eh][kk] = *reinterpret_cast<const bf16x8*>(bbase + eh * 16 * S_DIM + kk * 32);

            const f32x4 zero = {0.f, 0.f, 0.f, 0.f};
            f32x4 acc[2][2];
            acc[0][0] = zero; acc[0][1] = zero; acc[1][0] = zero; acc[1][1] = zero;
            #pragma unroll
            for (int kk = 0; kk < 4; ++kk) {
                acc[0][0] = __builtin_amdgcn_mfma_f32_16x16x32_bf16(afr[0][kk], bfr[0][kk], acc[0][0], 0, 0, 0);
                acc[0][1] = __builtin_amdgcn_mfma_f32_16x16x32_bf16(afr[0][kk], bfr[1][kk], acc[0][1], 0, 0, 0);
                acc[1][0] = __builtin_amdgcn_mfma_f32_16x16x32_bf16(afr[1][kk], bfr[0][kk], acc[1][0], 0, 0, 0);
                acc[1][1] = __builtin_amdgcn_mfma_f32_16x16x32_bf16(afr[1][kk], bfr[1][kk], acc[1][1], 0, 0, 0);
            }
            const int pair = wave * 4 + jj;            // 0..31 within half
            char* rowb = ldsb + pair * 2048;
            const int psw = (pair & 7) << 4;
            #pragma unroll
            for (int ch = 0; ch < 2; ++ch)
                #pragma unroll
                for (int eh = 0; eh < 2; ++eh) {
                    const int e  = eh * 16 + l16;          // D col = e
                    const int c0 = ch * 16 + l4 * 4;       // D rows = 4 consecutive c
                    const int byte = (e * 64 + c0 * 2) ^ ((e & 3) << 4) ^ psw;
                    ushort4 o;
                    o.x = f2bf(acc[ch][eh][0]);
                    o.y = f2bf(acc[ch][eh][1]);
                    o.z = f2bf(acc[ch][eh][2]);
                    o.w = f2bf(acc[ch][eh][3]);
                    *reinterpret_cast<ushort4*>(rowb + byte) = o;
                }
        }
        __syncthreads();

        // ---- phase 2: [32 pairs x 1024] @ wTp^T -> [32 x 128] ----
        {
            const __hip_bfloat16* wbase = wT + (size_t)(wave * 16 + l16) * 1024 + l4 * 8;
            const f32x4 zero = {0.f, 0.f, 0.f, 0.f};
            f32x4 pacc[2];
            pacc[0] = zero; pacc[1] = zero;
            #pragma unroll 4
            for (int kb = 0; kb < 32; ++kb) {
                const bf16x8 bfc = *reinterpret_cast<const bf16x8*>(wbase + kb * 32);
                #pragma unroll
                for (int mt = 0; mt < 2; ++mt) {
                    const int pr = mt * 16 + l16;
                    const bf16x8 af = *reinterpret_cast<const bf16x8*>(
                        ldsb + pr * 2048 +
                        ((kb * 64 + l4 * 16) ^ ((kb & 3) << 4) ^ ((pr & 7) << 4)));
                    pacc[mt] = __builtin_amdgcn_mfma_f32_16x16x32_bf16(af, bfc, pacc[mt], 0, 0, 0);
                }
            }
            const int z = wave * 16 + l16;
            const float bo = b_out[z];
            #pragma unroll
            for (int mt = 0; mt < 2; ++mt) {
                #pragma unroll
                for (int t = 0; t < 4; ++t) {
                    const int pl = mt * 16 + l4 * 4 + t;          // pair-local
                    const int oi = i0 + (pl >> 2), oj = j0 + half * 4 + (pl & 3);
                    out[((size_t)oi * R_DIM + oj) * CZ + z] =
                        (pacc[mt][t] + bo) * recip[oi * R_DIM + oj];
                }
            }
        }
        __syncthreads();   // protect next half's phase-1 writes
    }
}

// ---------------------------------------------------------------------------
extern "C" void kernel_launch(void* const* d_in, const int* in_sizes, int n_in,
                              void* d_out, int out_size, void* d_ws, size_t ws_size,
                              hipStream_t stream)
{
    const float* m     = (const float*)d_in[0];
    const float* mask  = (const float*)d_in[1];
    const float* ln_s  = (const float*)d_in[2];
    const float* ln_b  = (const float*)d_in[3];
    const float* w1    = (const float*)d_in[4];
    const float* b1    = (const float*)d_in[5];
    const float* w2    = (const float*)d_in[6];
    const float* b2    = (const float*)d_in[7];
    const float* w_out = (const float*)d_in[8];
    const float* b_out = (const float*)d_in[9];
    float* out = (float*)d_out;

    char* ws = (char*)d_ws;
    __hip_bfloat16* a_t  = (__hip_bfloat16*)(ws);                                    // 2 MB
    __hip_bfloat16* b_t  = (__hip_bfloat16*)(ws + (size_t)(2u << 20));               // 2 MB
    __hip_bfloat16* wT   = (__hip_bfloat16*)(ws + (size_t)(4u << 20));               // 256 KB
    float*          rcp  = (float*)(ws + (size_t)(4u << 20) + (size_t)(256u << 10)); // 256 KB
    __hip_bfloat16* w12T = (__hip_bfloat16*)(ws + (size_t)(4u << 20) + (size_t)(512u << 10)); // 32 KB

    prep_kernel<<<832, 256, 0, stream>>>(w1, w2, w_out, mask, w12T, wT, rcp);
    ln_proj_kernel<<<1024, 256, 0, stream>>>(m, mask, ln_s, ln_b, w12T, b1, b2, a_t, b_t);
    fused_kernel<<<dim3(32, 32), 512, 0, stream>>>(a_t, b_t, wT, b_out, rcp, out);
}